// Round 2
// baseline (67825.226 us; speedup 1.0000x reference)
//
#include <hip/hip_runtime.h>
#include <math.h>

#define NB 128
#define KPH 3
#define MAXPER 48
#define MAXTOK 144
#define LATENT 128
#define HD 512
#define NMEM 8
#define NH 8
#define VOC 8000
#define CT 145
#define NBLK 256
#define SCALE 0.125f

// ---- device-coherent (agent-scope: bypass XCD L2, hit MALL) access ----
__device__ __forceinline__ float ldsc(const float* p) {
  return __hip_atomic_load(const_cast<float*>(p), __ATOMIC_RELAXED, __HIP_MEMORY_SCOPE_AGENT);
}
__device__ __forceinline__ void stsc(float* p, float v) {
  __hip_atomic_store(p, v, __ATOMIC_RELAXED, __HIP_MEMORY_SCOPE_AGENT);
}
__device__ __forceinline__ int ldsci(const int* p) {
  return __hip_atomic_load(const_cast<int*>(p), __ATOMIC_RELAXED, __HIP_MEMORY_SCOPE_AGENT);
}
__device__ __forceinline__ void stsci(int* p, int v) {
  __hip_atomic_store(p, v, __ATOMIC_RELAXED, __HIP_MEMORY_SCOPE_AGENT);
}

// global -> LDS async DMA, 4 B/lane, wave-uniform LDS base + lane*4
__device__ __forceinline__ void gload_lds(const float* g, float* l) {
  __builtin_amdgcn_global_load_lds(
      (const __attribute__((address_space(1))) unsigned int*)g,
      (__attribute__((address_space(3))) unsigned int*)l, 4, 0, 0);
}

// ======================= setup kernels (run once) ==========================

__global__ void k_zero(float* __restrict__ p, int n) {
  int i = blockIdx.x * blockDim.x + threadIdx.x;
  if (i < n) p[i] = 0.0f;
}

__global__ void k_wz(const float* __restrict__ z_seq, const float* __restrict__ zw,
                     float* __restrict__ out) {
  int i = blockIdx.x * blockDim.x + threadIdx.x;
  if (i < NB * KPH * LATENT) out[i] = zw[i >> 7] * z_seq[i];
}

__global__ void k_copy(const float* __restrict__ src, float* __restrict__ dst, int n) {
  int i = blockIdx.x * blockDim.x + threadIdx.x;
  if (i < n) dst[i] = src[i];
}

__global__ __launch_bounds__(256) void k_gemm(
    const float* __restrict__ A, int lda,
    const float* __restrict__ W, int ldw, int K,
    float* __restrict__ out, int ostride)
{
  __shared__ float As[32][36];
  __shared__ float Ws[32][64];
  const int t = threadIdx.x;
  const int c0 = blockIdx.x * 64, b0 = blockIdx.y * 32;
  const int c = t & 63, g = t >> 6;
  float acc[8] = {0,0,0,0,0,0,0,0};
  const int ra = t >> 3, ka = (t & 7) << 2;
  for (int k0 = 0; k0 < K; k0 += 32) {
    const float4 a4 = *reinterpret_cast<const float4*>(A + (size_t)(b0 + ra) * lda + k0 + ka);
    As[ra][ka] = a4.x; As[ra][ka+1] = a4.y; As[ra][ka+2] = a4.z; As[ra][ka+3] = a4.w;
    #pragma unroll
    for (int e = 0; e < 8; e++) {
      int li = t + e * 256;
      Ws[li >> 6][li & 63] = W[(size_t)(k0 + (li >> 6)) * ldw + c0 + (li & 63)];
    }
    __syncthreads();
    #pragma unroll
    for (int kk = 0; kk < 32; kk++) {
      float wv = Ws[kk][c];
      #pragma unroll
      for (int i = 0; i < 8; i++) acc[i] += As[g*8+i][kk] * wv;
    }
    __syncthreads();
  }
  #pragma unroll
  for (int i = 0; i < 8; i++)
    out[(size_t)(b0 + g * 8 + i) * ostride + c0 + c] = acc[i];
}

__global__ void k_init(const float* __restrict__ zw,
                       int* __restrict__ cur, int* __restrict__ tip, int* __restrict__ pos,
                       int* __restrict__ done, float* __restrict__ gf, int* __restrict__ iph,
                       int* __restrict__ nxt0, int* __restrict__ act)
{
  int b = blockIdx.x * blockDim.x + threadIdx.x;
  if (b < NB) {
    int a0 = zw[b*3+0] > 0.01f;
    act[b*3+0] = a0;
    act[b*3+1] = zw[b*3+1] > 0.01f;
    act[b*3+2] = zw[b*3+2] > 0.01f;
    cur[b] = 0; tip[b] = 0; pos[b] = 0; done[b] = !a0;   // version 0
    gf[b] = a0 ? 1.0f : 0.0f; iph[b] = 0;
    nxt0[b] = 1;                                          // BOS
  }
}

// ======================= persistent decode =================================

struct DecP {
  const float *temb, *Wq, *Wk, *Wv, *Wo, *Wco, *W1, *W2, *Wout;
  const float *MCK, *MCV, *WCAT;
  float *KC, *VC, *XS, *X2, *X3, *X, *Qb, *CQ, *CQ2, *H1, *GP, *PV, *GF;
  int *PI, *CUR, *TIP, *POS, *DONE, *IPH, *NXT0, *ACT;
  float *TOK, *GEN, *BND, *HID;
  unsigned *bar;
};

// hierarchical barrier: 64 arrival counters (NBLK/64 blocks each); block 0 wave 0
// detects, then 8 replicated go lines; others poll one.
__device__ __forceinline__ void gsync(unsigned* bar, unsigned epoch) {
  const int t = threadIdx.x, blk = blockIdx.x;
  __syncthreads();
  if (t == 0)
    __hip_atomic_fetch_add(&bar[(blk & 63) * 32], 1u,
                           __ATOMIC_RELAXED, __HIP_MEMORY_SCOPE_AGENT);
  if (blk == 0) {
    if (t < 64) {
      const unsigned tg = epoch * (NBLK / 64);
      while (__hip_atomic_load(&bar[t * 32], __ATOMIC_RELAXED, __HIP_MEMORY_SCOPE_AGENT) < tg)
        __builtin_amdgcn_s_sleep(2);
      if (t < 8)
        __hip_atomic_store(&bar[2048 + t * 32], epoch,
                           __ATOMIC_RELAXED, __HIP_MEMORY_SCOPE_AGENT);
    }
  } else if (t == 0) {
    while (__hip_atomic_load(&bar[2048 + (blk & 7) * 32],
                             __ATOMIC_RELAXED, __HIP_MEMORY_SCOPE_AGENT) < epoch)
      __builtin_amdgcn_s_sleep(8);
  }
  __syncthreads();
}

__global__ __launch_bounds__(256, 2) void k_decode(DecP p) {
  // ~80 KB LDS: W slab DMA double-buffer (128-wide rows; 64-col tiles use the
  // first half of each row), A^T slab (stride 36 = 144 B keeps float4 alignment
  // + max 2-way bank aliasing), misc scratch.
  __shared__ float WS[2][64][128];     // 64 KB
  __shared__ float At[64][36];         // 9 KB
  __shared__ float U[1280];            // 5 KB: attn aux / cross-attn scratch
  __shared__ int   snxt[16];

  const int t = threadIdx.x;
  const int blk = blockIdx.x;
  unsigned ep = 0;

  const int cg = t & 31, rg = t >> 5;   // compute-thread col/row groups
  const int wv = t >> 6, lc = t & 63;   // W staging: wave id, lane

  // ---- 16r x 64c fp32 GEMM, 2x2/thread via b64 LDS reads ------------------
  auto gemm22 = [&](int b0, int c0, const float* A, int lda, int kA0,
                    const float* W, int ldw, int kW0,
                    const float* R, int rs, float* out, int os, int dogelu) {
    const int sr = t & 15, sk = (t >> 4) << 2;     // A^T staging row / k-offset
    float acc[2][2] = {{0.f,0.f},{0.f,0.f}};
    float aP[4];
    const float* Ab = A + (size_t)(b0 + sr) * lda + kA0 + sk;
    #pragma unroll
    for (int u = 0; u < 4; u++) aP[u] = ldsc(Ab + u);
    #pragma unroll
    for (int e = 0; e < 16; e++)
      gload_lds(W + (size_t)(kW0 + wv * 16 + e) * ldw + c0 + lc, &WS[0][wv * 16 + e][0]);
    for (int j = 0; j < 8; j++) {
      const int cur = j & 1;
      #pragma unroll
      for (int u = 0; u < 4; u++) At[sk + u][sr] = aP[u];
      __syncthreads();                 // drains W DMA for slab j; At ready
      if (j < 7) {
        #pragma unroll
        for (int u = 0; u < 4; u++) aP[u] = ldsc(Ab + (j + 1) * 64 + u);
        #pragma unroll
        for (int e = 0; e < 16; e++)
          gload_lds(W + (size_t)(kW0 + (j + 1) * 64 + wv * 16 + e) * ldw + c0 + lc,
                    &WS[cur ^ 1][wv * 16 + e][0]);
      }
      #pragma unroll
      for (int kk = 0; kk < 64; kk++) {
        float2 av = *reinterpret_cast<const float2*>(&At[kk][rg * 2]);
        float2 bv = *reinterpret_cast<const float2*>(&WS[cur][kk][cg * 2]);
        acc[0][0] += av.x * bv.x; acc[0][1] += av.x * bv.y;
        acc[1][0] += av.y * bv.x; acc[1][1] += av.y * bv.y;
      }
      __syncthreads();
    }
    #pragma unroll
    for (int i = 0; i < 2; i++) {
      #pragma unroll
      for (int jj = 0; jj < 2; jj++) {
        float v = acc[i][jj];
        int br = b0 + rg * 2 + i, bc = c0 + cg * 2 + jj;
        if (R) v += ldsc(R + (size_t)br * rs + bc);
        if (dogelu) {
          float x3 = v * v * v;
          v = 0.5f * v * (1.0f + tanhf(0.7978845608028654f * (v + 0.044715f * x3)));
        }
        stsc(out + (size_t)br * os + bc, v);
      }
    }
  };

  // ---- same, A rows gathered from temb via snxt (QKV) ---------------------
  auto gemm22g = [&](int b0, int c0, const float* W, float* out, int os) {
    const int sr = t & 15, sk = (t >> 4) << 2;
    float acc[2][2] = {{0.f,0.f},{0.f,0.f}};
    const float* Ar = p.temb + (size_t)snxt[sr] * 512;
    float4 aP = *reinterpret_cast<const float4*>(Ar + sk);
    #pragma unroll
    for (int e = 0; e < 16; e++)
      gload_lds(W + (size_t)(wv * 16 + e) * 512 + c0 + lc, &WS[0][wv * 16 + e][0]);
    for (int j = 0; j < 8; j++) {
      const int cur = j & 1;
      At[sk + 0][sr] = aP.x; At[sk + 1][sr] = aP.y;
      At[sk + 2][sr] = aP.z; At[sk + 3][sr] = aP.w;
      __syncthreads();
      if (j < 7) {
        aP = *reinterpret_cast<const float4*>(Ar + (j + 1) * 64 + sk);
        #pragma unroll
        for (int e = 0; e < 16; e++)
          gload_lds(W + (size_t)((j + 1) * 64 + wv * 16 + e) * 512 + c0 + lc,
                    &WS[cur ^ 1][wv * 16 + e][0]);
      }
      #pragma unroll
      for (int kk = 0; kk < 64; kk++) {
        float2 av = *reinterpret_cast<const float2*>(&At[kk][rg * 2]);
        float2 bv = *reinterpret_cast<const float2*>(&WS[cur][kk][cg * 2]);
        acc[0][0] += av.x * bv.x; acc[0][1] += av.x * bv.y;
        acc[1][0] += av.y * bv.x; acc[1][1] += av.y * bv.y;
      }
      __syncthreads();
    }
    #pragma unroll
    for (int i = 0; i < 2; i++)
      #pragma unroll
      for (int jj = 0; jj < 2; jj++)
        stsc(out + (size_t)(b0 + rg * 2 + i) * os + c0 + cg * 2 + jj, acc[i][jj]);
  };

  // ---- logits 32r x 128c, 4x4/thread via b128 LDS reads, + argmax partial --
  auto logits32 = [&](int ct, int rt) {
    const int sr = t & 31, sk = (t >> 5) << 3;
    const int b0 = rt * 32, c0 = ct * 128;
    float acc[4][4] = {};
    float aR[8];
    const float* Ab = p.X + (size_t)(b0 + sr) * 512 + sk;
    #pragma unroll
    for (int u = 0; u < 8; u++) aR[u] = ldsc(Ab + u);
    auto wrow = [&](int row, int half) -> const float* {
      int col = c0 + half * 64 + lc;
      if (col >= VOC) col = VOC - 1;   // tail tile: clamp (values masked later)
      return p.Wout + (size_t)row * VOC + col;
    };
    #pragma unroll
    for (int e = 0; e < 16; e++) {
      int row = wv * 16 + e;
      gload_lds(wrow(row, 0), &WS[0][row][0]);
      gload_lds(wrow(row, 1), &WS[0][row][64]);
    }
    for (int j = 0; j < 8; j++) {
      const int cur = j & 1;
      #pragma unroll
      for (int u = 0; u < 8; u++) At[sk + u][sr] = aR[u];
      __syncthreads();
      if (j < 7) {
        #pragma unroll
        for (int u = 0; u < 8; u++) aR[u] = ldsc(Ab + (j + 1) * 64 + u);
        #pragma unroll
        for (int e = 0; e < 16; e++) {
          int row = wv * 16 + e;
          gload_lds(wrow((j + 1) * 64 + row, 0), &WS[cur ^ 1][row][0]);
          gload_lds(wrow((j + 1) * 64 + row, 1), &WS[cur ^ 1][row][64]);
        }
      }
      #pragma unroll
      for (int kk = 0; kk < 64; kk++) {
        float4 av = *reinterpret_cast<const float4*>(&At[kk][rg * 4]);
        float4 wq = *reinterpret_cast<const float4*>(&WS[cur][kk][cg * 4]);
        float a4[4] = {av.x, av.y, av.z, av.w};
        float w4[4] = {wq.x, wq.y, wq.z, wq.w};
        #pragma unroll
        for (int i = 0; i < 4; i++)
          #pragma unroll
          for (int u = 0; u < 4; u++) acc[i][u] += a4[i] * w4[u];
      }
      __syncthreads();
    }
    // per-row argmax partial over this tile's 128 cols (first-index tiebreak)
    #pragma unroll
    for (int i = 0; i < 4; i++) {
      float bv = -INFINITY; int bix = 0x7fffffff;
      #pragma unroll
      for (int u = 0; u < 4; u++) {
        int c = c0 + cg * 4 + u;
        float v = (c < VOC) ? acc[i][u] : -INFINITY;
        if (v > bv) { bv = v; bix = c; }    // ascending u -> first index wins
      }
      #pragma unroll
      for (int off = 16; off; off >>= 1) {
        float v2 = __shfl_xor(bv, off, 64);
        int i2 = __shfl_xor(bix, off, 64);
        if (v2 > bv || (v2 == bv && i2 < bix)) { bv = v2; bix = i2; }
      }
      if (cg == 0) {
        stsc(&p.PV[(size_t)(b0 + rg * 4 + i) * 64 + ct], bv);
        stsci(&p.PI[(size_t)(b0 + rg * 4 + i) * 64 + ct], bix);
      }
    }
  };

  // argmax-finish + state machine for rows b0..b0+15 (redundant across blocks;
  // identical values -> benign). desig block also writes outputs.
  auto state_phase = [&](int s, int b0, int desig) {
    const int r = t >> 4, j = t & 15, b = b0 + r;
    const int vOld = (s - 1) & 1, vNew = s & 1;
    if (s > 0) {
      float bv = -INFINITY; int bix = 0x7fffffff;
      for (int i = j; i < 63; i += 16) {
        float v = ldsc(&p.PV[(size_t)b * 64 + i]);
        int  id = ldsci(&p.PI[(size_t)b * 64 + i]);
        if (v > bv || (v == bv && id < bix)) { bv = v; bix = id; }
      }
      #pragma unroll
      for (int off = 8; off; off >>= 1) {
        float v2 = __shfl_xor(bv, off, 64);
        int   i2 = __shfl_xor(bix, off, 64);
        if (v2 > bv || (v2 == bv && i2 < bix)) { bv = v2; bix = i2; }
      }
      if (j == 0) {
        int nxt = bix;
        int dn = ldsci(&p.DONE[vOld*NB+b]); int live = !dn;
        int pp = ldsci(&p.POS[vOld*NB+b]);
        int tp = ldsci(&p.TIP[vOld*NB+b]);
        int cp = ldsci(&p.CUR[vOld*NB+b]);
        if (desig && pp < MAXTOK) {
          p.TOK[(size_t)b*MAXTOK+pp] = live ? (float)nxt : 0.0f;
          p.GEN[(size_t)b*MAXTOK+pp] = live ? 1.0f : 0.0f;
        }
        pp += live; tp += live;
        int eos = (nxt == 2) && (tp >= 1);
        int sw = (eos || (tp >= MAXPER)) && live;
        cp += sw;
        if (sw) tp = 0;
        int cpc = cp < 2 ? cp : 2;
        if (desig && sw && (cp < KPH)) p.BND[(size_t)b*KPH+cpc] = (float)pp;
        dn = dn || (cp >= KPH) || (sw && !p.ACT[b*3+cpc]);
        stsci(&p.CUR[vNew*NB+b], cp);
        stsci(&p.TIP[vNew*NB+b], tp);
        stsci(&p.POS[vNew*NB+b], pp);
        stsci(&p.DONE[vNew*NB+b], dn);
        stsc(&p.GF[vNew*NB+b], (p.ACT[b*3+cpc] && !dn) ? 1.0f : 0.0f);
        stsci(&p.IPH[vNew*NB+b], cpc);
        snxt[r] = nxt;
      }
    } else {
      if (j == 0) snxt[r] = p.NXT0[b];
    }
    __syncthreads();
  };

  for (int s = 0; s < MAXTOK; s++) {
    // ---- A': state (t=s-1) + Q,K,V projections (slot s); 192 blocks ----
    if (blk < 192) {
      int by = blk / 24, ct = blk - by * 24;   // by: row group, ct: 0..23
      int b0 = by * 16;
      int m = ct >> 3, bx = ct & 7;            // m: 0=Q 1=K 2=V
      state_phase(s, b0, ct == 0);
      if (ct == 0) {                           // XS XIN copy
        #pragma unroll
        for (int rep = 0; rep < 8; rep++) {
          int q = rep * 256 + t, rr = q >> 7, c4 = (q & 127) << 2;
          float4 e4 = *reinterpret_cast<const float4*>(p.temb + (size_t)snxt[rr] * 512 + c4);
          float* d = &p.XS[(size_t)(b0 + rr) * 1024 + c4];
          stsc(d, e4.x); stsc(d + 1, e4.y); stsc(d + 2, e4.z); stsc(d + 3, e4.w);
        }
      }
      if (m == 0)      gemm22g(b0, bx * 64, p.Wq, p.Qb, 512);
      else if (m == 1) gemm22g(b0, bx * 64, p.Wk, p.KC + s * 512, CT * 512);
      else             gemm22g(b0, bx * 64, p.Wv, p.VC + s * 512, CT * 512);
    }
    gsync(p.bar, ++ep);

    // ---- B: self-attention, T = s+1, one wave per (b,h); all 256 blocks ----
    {
      float (*aux)[224] = (float(*)[224])U;
      const int T = s + 1;
      int lane = t & 63, w = t >> 6;
      int task = blk * 4 + w, b = task >> 3, h = task & 7;
      float* ql = aux[w];
      float* sc = aux[w] + 64;
      ql[lane] = ldsc(&p.Qb[(size_t)b * 512 + h * 64 + lane]);
      __syncthreads();
      float lmax = -INFINITY;
      for (int s0 = lane; s0 < T; s0 += 64) {
        const float4* kp = reinterpret_cast<const float4*>(p.KC + ((size_t)b * CT + s0) * 512 + h * 64);
        float d = 0.0f;
        #pragma unroll
        for (int e = 0; e < 16; e++) {
          float4 k4 = kp[e];
          d += ql[4*e]*k4.x + ql[4*e+1]*k4.y + ql[4*e+2]*k4.z + ql[4*e+3]*k4.w;
        }
        d *= SCALE;
        sc[s0] = d;
        lmax = fmaxf(lmax, d);
      }
      #pragma unroll
      for (int off = 32; off; off >>= 1) lmax = fmaxf(lmax, __shfl_xor(lmax, off, 64));
      float lsum = 0.0f;
      for (int s0 = lane; s0 < T; s0 += 64) {
        float e = expf(sc[s0] - lmax);
        sc[s0] = e; lsum += e;
      }
      #pragma unroll
      for (int off = 32; off; off >>= 1) lsum += __shfl_xor(lsum, off, 64);
      __syncthreads();
      float inv = 1.0f / lsum;
      float acc = 0.0f;
      const float* vb = p.VC + (size_t)b * CT * 512 + h * 64 + lane;
      for (int s0 = 0; s0 < T; s0++) acc += sc[s0] * vb[(size_t)s0 * 512];
      stsc(&p.XS[(size_t)b * 1024 + 512 + h * 64 + lane], acc * inv);
    }
    gsync(p.bar, ++ep);

    // ---- C: X2 = XIN + SA@Wo (64 blk); CQ = [XIN|SA]@WCAT split-K2 (128 blk) ----
    if (blk < 64) {
      int ct = blk & 7, rt = blk >> 3;
      gemm22(rt * 16, ct * 64, p.XS + 512, 1024, 0, p.Wo, 512, 0,
             p.XS, 1024, p.X2, 512, 0);
    } else if (blk < 192) {
      int loc = blk - 64, kh = loc >> 6, l2 = loc & 63;
      int ct = l2 & 7, rt = l2 >> 3;
      gemm22(rt * 16, ct * 64, p.XS, 1024, kh * 512, p.WCAT, 512, kh * 512,
             nullptr, 0, kh ? p.CQ2 : p.CQ, 512, 0);
    }
    gsync(p.bar, ++ep);

    // ---- E': fused cross-attention + X3 = X2 + CA@Wco, one block per b ----
    if (blk < NB) {
      const int b = blk;
      const int vNew = s & 1;
      float* cq  = U;            // 512
      float* ca  = U + 512;      // 512
      float* scs = U + 1024;     // 64
      cq[t]       = ldsc(&p.CQ[(size_t)b * 512 + t])       + ldsc(&p.CQ2[(size_t)b * 512 + t]);
      cq[t + 256] = ldsc(&p.CQ[(size_t)b * 512 + t + 256]) + ldsc(&p.CQ2[(size_t)b * 512 + t + 256]);
      __syncthreads();
      float gate = ldsc(&p.GF[vNew*NB+b]);
      int ip = ldsci(&p.IPH[vNew*NB+b]);
      const float* mk = p.MCK + (size_t)(b * KPH + ip) * NMEM * 512;
      if (t < 64) {
        int h = t >> 3, m = t & 7;
        const float4* kp = reinterpret_cast<const float4*>(mk + m * 512 + h * 64);
        float d = 0.0f;
        #pragma unroll
        for (int e = 0; e < 16; e++) {
          float4 k4 = kp[e];
          d += cq[h*64+4*e]*k4.x + cq[h*64+4*e+1]*k4.y + cq[h*64+4*e+2]*k4.z + cq[h*64+4*e+3]*k4.w;
        }
        scs[t] = d * SCALE * gate;
      }
      __syncthreads();
      const float* mv = p.MCV + (size_t)(b * KPH + ip) * NMEM * 512;
      #pragma unroll
      for (int half = 0; half < 2; half++) {
        int c = t + half * 256;
        int h = c >> 6;
        float mx = scs[h*8];
        #pragma unroll
        for (int m = 1; m < 8; m++) mx = fmaxf(mx, scs[h*8+m]);
        float ee[8]; float sum = 0.0f;
        #pragma unroll
        for (int m = 0; m < 8; m++) { ee[m] = expf(scs[h*8+m] - mx); sum += ee[m]; }
        float a = 0.0f;
        #pragma unroll
        for (int m = 0; m < 8; m++) a += ee[m] * mv[(size_t)m * 512 + c];
        ca[c] = gate * a / sum;
      }
      __syncthreads();
      // X3[b][c] = X2[b][c] + sum_k ca[k]*Wco[k][c]   (serial k, fixed order)
      #pragma unroll
      for (int half = 0; half < 2; half++) {
        int c = t + half * 256;
        float acc = 0.0f;
        const float* wc = p.Wco + c;
        for (int k = 0; k < 512; k++) acc += ca[k] * wc[(size_t)k * 512];
        stsc(&p.X3[(size_t)b * 512 + c], acc + ldsc(&p.X2[(size_t)b * 512 + c]));
      }
    }
    gsync(p.bar, ++ep);

    // ---- F: H1 = gelu(X3@W1), N=2048, all 256 blocks ----
    {
      int ct = blk & 31, rt = blk >> 5;
      gemm22(rt * 16, ct * 64, p.X3, 512, 0, p.W1, 2048, 0,
             nullptr, 0, p.H1, 2048, 1);
    }
    gsync(p.bar, ++ep);

    // ---- G: GP[ks] = H1[:,ks*512:+512]@W2[ks*512:+512,:], split-K4 ----
    {
      int ks = blk >> 6, l2 = blk & 63, ct = l2 & 7, rt = l2 >> 3;
      gemm22(rt * 16, ct * 64, p.H1, 2048, ks * 512, p.W2, 512, ks * 512,
             nullptr, 0, p.GP + (size_t)ks * NB * 512, 512, 0);
    }
    gsync(p.bar, ++ep);

    // ---- R: X = X3 + GP0+GP1+GP2+GP3 (fixed order); HID[s] = X ----
    {
      int el = blk * 256 + t;
      float v = ldsc(&p.X3[el])
              + ldsc(&p.GP[el]) + ldsc(&p.GP[NB*512 + el])
              + ldsc(&p.GP[2*NB*512 + el]) + ldsc(&p.GP[3*NB*512 + el]);
      stsc(&p.X[el], v);
      p.HID[(size_t)s * NB * 512 + el] = v;
    }
    gsync(p.bar, ++ep);

    // ---- H: logits + argmax partials; col tiles XCD-pinned (ct%8==blk%8) ----
    {
      int ct = ((blk >> 3) & 7) * 8 + (blk & 7), rt = blk >> 6;
      if (ct < 63) logits32(ct, rt);
    }
    gsync(p.bar, ++ep);
  }

  // ---- epilogue: state machine t=143 + final TOK/GEN/BND ----
  if (blk < 8) {
    state_phase(MAXTOK, blk * 16, 1);
  }
}

// ======================= host ==============================================

extern "C" void kernel_launch(void* const* d_in, const int* in_sizes, int n_in,
                              void* d_out, int out_size, void* d_ws, size_t ws_size,
                              hipStream_t stream)
{
  const float* z_seq = (const float*)d_in[0];
  const float* z_w   = (const float*)d_in[1];
  const float* W_l2d = (const float*)d_in[2];
  const float* temb  = (const float*)d_in[3];
  const float* Wq  = (const float*)d_in[4];
  const float* Wk  = (const float*)d_in[5];
  const float* Wv  = (const float*)d_in[6];
  const float* Wo  = (const float*)d_in[7];
  const float* Wcq = (const float*)d_in[8];
  const float* Wck = (const float*)d_in[9];
  const float* Wcv = (const float*)d_in[10];
  const float* Wco = (const float*)d_in[11];
  const float* W1  = (const float*)d_in[12];
  const float* W2  = (const float*)d_in[13];
  const float* Wout= (const float*)d_in[14];

  float* fw = (float*)d_ws;
  size_t o = 4096;   // first 4096 words: barrier counters + go lines
  auto alloc = [&](size_t n) { float* r = fw + o; o += (n + 63) & ~(size_t)63; return r; };
  float* MCK = alloc((size_t)NB*KPH*NMEM*HD);
  float* MCV = alloc((size_t)NB*KPH*NMEM*HD);
  float* MEM = alloc((size_t)NB*KPH*NMEM*HD);   // reused as WCAT + GP/CQ2 after setup
  float* KC  = alloc((size_t)NB*CT*HD);
  float* VC  = alloc((size_t)NB*CT*HD);
  float* XS  = alloc((size_t)NB*1024);          // [XIN | SA]
  float* X2  = alloc((size_t)NB*HD);
  float* X3  = alloc((size_t)NB*HD);
  float* X   = alloc((size_t)NB*HD);
  float* Qb  = alloc((size_t)NB*HD);
  float* CQ  = alloc((size_t)NB*HD);
  float* H1  = alloc((size_t)NB*4*HD);
  float* WZ  = alloc((size_t)NB*KPH*LATENT);
  float* PV  = alloc((size_t)NB*64);
  float* GF  = alloc(2*NB);
  int* ib = (int*)alloc(0);
  size_t io = 0;
  auto ialloc = [&](size_t n) { int* r = ib + io; io += (n + 63) & ~(size_t)63; return r; };
  int* PI   = ialloc((size_t)NB*64);
  int* CUR  = ialloc(2*NB);
  int* TIP  = ialloc(2*NB);
  int* POS  = ialloc(2*NB);
  int* DONE = ialloc(2*NB);
  int* IPH  = ialloc(2*NB);
  int* NXT0 = ialloc(NB);
  int* ACT  = ialloc(NB*KPH);

  // MEM region (1,572,864 floats) layout after setup:
  //   [0 .. 524288)        WCAT = [Wcq ; Wo@Wcq]  (1024 x 512)
  //   [524288 .. 786432)   GP   (4 * NB * HD = 262144 floats, split-K4 partials)
  //   [786432 .. 851968)   CQ2  (NB * HD = 65536 floats, split-K2 partial)
  // memories data in MEM is dead once MCK/MCV are built, so this is free space
  // and keeps total workspace usage within the previously-proven envelope.
  float* WCAT = MEM;
  float* GP   = MEM + (size_t)1024*512;
  float* CQ2  = GP  + (size_t)4*NB*HD;

  float* out_f = (float*)d_out;
  float* TOK  = out_f;
  float* GEN  = out_f + NB*MAXTOK;
  float* BND  = out_f + 2*NB*MAXTOK;
  float* HID  = out_f + 2*NB*MAXTOK + NB*KPH;

  // ---- one-time setup (plain kernels; dispatch boundaries give coherence) ----
  k_zero<<<16, 256, 0, stream>>>(fw, 4096);                               // barrier
  int nz = 2*NB*MAXTOK + NB*KPH;
  k_zero<<<(nz + 255)/256, 256, 0, stream>>>(out_f, nz);                  // tok/gen/bnd
  k_wz<<<(NB*KPH*LATENT + 255)/256, 256, 0, stream>>>(z_seq, z_w, WZ);
  k_gemm<<<dim3(64,12),256,0,stream>>>(WZ, 128, W_l2d, 4096, 128, MEM, 4096);
  k_gemm<<<dim3(8,96),256,0,stream>>>(MEM, 512, Wck, 512, 512, MCK, 512);
  k_gemm<<<dim3(8,96),256,0,stream>>>(MEM, 512, Wcv, 512, 512, MCV, 512);
  k_gemm<<<dim3(8,16),256,0,stream>>>(Wo, 512, Wcq, 512, 512, WCAT + (size_t)512*512, 512);
  k_copy<<<(512*512 + 255)/256, 256, 0, stream>>>(Wcq, WCAT, 512*512);
  k_init<<<1,128,0,stream>>>(z_w, CUR, TIP, POS, DONE, GF, IPH, NXT0, ACT);

  // ---- persistent decode: 256 blocks, 1/CU ----
  DecP prm;
  prm.temb = temb; prm.Wq = Wq; prm.Wk = Wk; prm.Wv = Wv; prm.Wo = Wo;
  prm.Wco = Wco; prm.W1 = W1; prm.W2 = W2; prm.Wout = Wout;
  prm.MCK = MCK; prm.MCV = MCV; prm.WCAT = WCAT;
  prm.KC = KC; prm.VC = VC; prm.XS = XS; prm.X2 = X2; prm.X3 = X3; prm.X = X;
  prm.Qb = Qb; prm.CQ = CQ; prm.CQ2 = CQ2; prm.H1 = H1; prm.GP = GP;
  prm.PV = PV; prm.GF = GF;
  prm.PI = PI; prm.CUR = CUR; prm.TIP = TIP; prm.POS = POS; prm.DONE = DONE;
  prm.IPH = IPH; prm.NXT0 = NXT0; prm.ACT = ACT;
  prm.TOK = TOK; prm.GEN = GEN; prm.BND = BND; prm.HID = HID;
  prm.bar = (unsigned*)d_ws;

  k_decode<<<dim3(NBLK), dim3(256), 0, stream>>>(prm);
}